// Round 9
// baseline (84.180 us; speedup 1.0000x reference)
//
#include <hip/hip_runtime.h>

// DCT2D, LDS-staged reads. Each WAVE owns 16 consecutive 8x8 blocks (4 KB):
//   4 x global_load_dwordx4 (1 KB contiguous per instruction, zero fragmentation)
//   -> 4 x ds_write_b128 into a private 4 KB LDS slice, XOR-swizzled
//   -> per 8-lane group: 16 x ds_read_b32 column reads (2-way bank alias = free)
//   -> pass1 local DCT, one lane-transpose (DPP shuffles), pass2 local DCT
//   -> 4 x nontemporal dwordx4 row stores (WRITE_SIZE already ideal at 210 MB).
// Swizzle: word W in [0,1024), W' = W ^ (((W>>7)&3)<<3).  For column reads
// W = 128 g + 8 xx + r  (W>>7 == g), so W' = 128 g + 8 (xx^(g&3)) + r —
// 8 loop-invariant per-lane addresses, no runtime register indexing.
// cs[a][b] = c[a][b]*alpha[b]*0.5 recovered exactly from inputs:
//   c[a][b] = dct_tensor[a,0,b,0] (c[0][0]==1); alpha[b]*0.5 = scale[b,0]*2*sqrt(2)

typedef float vfloat4 __attribute__((ext_vector_type(4)));

__device__ __forceinline__ float uniformf(float v)
{
    return __int_as_float(__builtin_amdgcn_readfirstlane(__float_as_int(v)));
}

__device__ __forceinline__ void xpose8(float a[8], bool h1, bool h2, bool h4)
{
#pragma unroll
    for (int j = 0; j < 8; j += 2) {
        const int k = j + 1;
        float fj = __shfl_xor(a[k], 1);
        float fk = __shfl_xor(a[j], 1);
        float nj = h1 ? fj : a[j];
        float nk = h1 ? a[k] : fk;
        a[j] = nj; a[k] = nk;
    }
#pragma unroll
    for (int jj = 0; jj < 8; jj += 4) {
#pragma unroll
        for (int j0 = 0; j0 < 2; ++j0) {
            const int j = jj + j0, k = j + 2;
            float fj = __shfl_xor(a[k], 2);
            float fk = __shfl_xor(a[j], 2);
            float nj = h2 ? fj : a[j];
            float nk = h2 ? a[k] : fk;
            a[j] = nj; a[k] = nk;
        }
    }
#pragma unroll
    for (int j = 0; j < 4; ++j) {
        const int k = j + 4;
        float fj = __shfl_xor(a[k], 4);
        float fk = __shfl_xor(a[j], 4);
        float nj = h4 ? fj : a[j];
        float nk = h4 ? a[k] : fk;
        a[j] = nj; a[k] = nk;
    }
}

// column data o[8] (already -128'd) -> output row `lane` res[8]
__device__ __forceinline__ void dct_block(const float o[8], float res[8],
                                          const float cs[8][8],
                                          bool h1, bool h2, bool h4)
{
    float t[8];
#pragma unroll
    for (int u = 0; u < 8; ++u) {
        float s = 0.0f;
#pragma unroll
        for (int xx = 0; xx < 8; ++xx) s = fmaf(o[xx], cs[xx][u], s);
        t[u] = s;
    }
    xpose8(t, h1, h2, h4);
#pragma unroll
    for (int v = 0; v < 8; ++v) {
        float s = 0.0f;
#pragma unroll
        for (int y = 0; y < 8; ++y) s = fmaf(t[y], cs[y][v], s);
        res[v] = s;
    }
}

__global__ __launch_bounds__(256) void dct2d_kernel(
    const float* __restrict__ x,
    const float* __restrict__ dct,     // [8,8,8,8] = c[x,u]*c[y,v]
    const float* __restrict__ scale,   // [8,8]
    float* __restrict__ out,
    int nblocks)
{
    __shared__ float lds_all[4][1024];           // 4 KB private slice per wave

    const int tid   = blockIdx.x * blockDim.x + threadIdx.x;
    const int lane  = threadIdx.x & 63;
    const int wslot = threadIdx.x >> 6;          // wave within WG (0..3)
    const int gwid  = tid >> 6;                  // global wave id
    const int nwaves = (gridDim.x * blockDim.x) >> 6;
    const int g    = lane >> 3;                  // 8-lane group (0..7)
    const int r    = lane & 7;                   // column index within block
    const int kg   = g & 3;                      // read-swizzle key component

    float* L = lds_all[wslot];

    // wave-uniform folded constant matrix, forced to SGPRs
    float cs[8][8];
#pragma unroll
    for (int b = 0; b < 8; ++b) {
        const float a05 = scale[b * 8] * 2.8284271247461903f;  // alpha[b]*0.5
#pragma unroll
        for (int a = 0; a < 8; ++a)
            cs[a][b] = uniformf(dct[a * 512 + b * 8] * a05);   // c[a][b]*a05
    }

    const bool h1 = (r & 1) != 0;
    const bool h2 = (r & 2) != 0;
    const bool h4 = (r & 4) != 0;

    // loop-invariant addresses
    // write side: chunk i word addr Wt = i*256 + lane*4, swizzled
    int wws[4];
#pragma unroll
    for (int i = 0; i < 4; ++i) {
        int Wt = i * 256 + lane * 4;
        wws[i] = Wt ^ (((Wt >> 7) & 3) << 3);
    }
    // read side: row xx of block A (=2g) at word 128g + 8*(xx^kg) + r
    int aoff[8];
#pragma unroll
    for (int xx = 0; xx < 8; ++xx) aoff[xx] = 128 * g + 8 * (xx ^ kg) + r;

    const int ntiles = nblocks >> 4;             // 16 blocks per tile
    for (int tile = gwid; tile < ntiles; tile += nwaves) {
        // 1) fully-coalesced global read of the 4 KB tile
        const vfloat4* src = reinterpret_cast<const vfloat4*>(x + (size_t)tile * 1024);
        vfloat4 v0 = src[lane];
        vfloat4 v1 = src[64 + lane];
        vfloat4 v2 = src[128 + lane];
        vfloat4 v3 = src[192 + lane];
        // 2) stage into swizzled LDS slice
        *reinterpret_cast<vfloat4*>(&L[wws[0]]) = v0;
        *reinterpret_cast<vfloat4*>(&L[wws[1]]) = v1;
        *reinterpret_cast<vfloat4*>(&L[wws[2]]) = v2;
        *reinterpret_cast<vfloat4*>(&L[wws[3]]) = v3;
        // 3) column reads (compiler inserts lgkmcnt; per-wave private slice)
        float oA[8], oB[8];
#pragma unroll
        for (int xx = 0; xx < 8; ++xx) {
            oA[xx] = L[aoff[xx]]      - 128.0f;   // block 2g
            oB[xx] = L[aoff[xx] + 64] - 128.0f;   // block 2g+1 (64 words later, same key)
        }
        // 4) two local DCTs
        float rA[8], rB[8];
        dct_block(oA, rA, cs, h1, h2, h4);
        dct_block(oB, rB, cs, h1, h2, h4);
        // 5) nontemporal row stores (pattern proven WRITE-ideal)
        float* op = out + (size_t)(tile * 16 + 2 * g) * 64 + r * 8;
        vfloat4 sA0 = { rA[0], rA[1], rA[2], rA[3] };
        vfloat4 sA1 = { rA[4], rA[5], rA[6], rA[7] };
        vfloat4 sB0 = { rB[0], rB[1], rB[2], rB[3] };
        vfloat4 sB1 = { rB[4], rB[5], rB[6], rB[7] };
        __builtin_nontemporal_store(sA0, reinterpret_cast<vfloat4*>(op));
        __builtin_nontemporal_store(sA1, reinterpret_cast<vfloat4*>(op + 4));
        __builtin_nontemporal_store(sB0, reinterpret_cast<vfloat4*>(op + 64));
        __builtin_nontemporal_store(sB1, reinterpret_cast<vfloat4*>(op + 68));
    }

    // generic tail for nblocks % 16 != 0 (not hit at 786432): direct column loads
    const int rem  = nblocks & 15;
    if (rem && gwid == 0) {
        const int base = ntiles * 16;
#pragma unroll
        for (int pass = 0; pass < 2; ++pass) {
            int bi = base + g + pass * 8;
            if (bi < nblocks) {
                const float* p = x + (size_t)bi * 64 + r;
                float o[8];
#pragma unroll
                for (int xx = 0; xx < 8; ++xx) o[xx] = p[xx * 8] - 128.0f;
                float rr[8];
                dct_block(o, rr, cs, h1, h2, h4);
                float* op = out + (size_t)bi * 64 + r * 8;
                vfloat4 s0 = { rr[0], rr[1], rr[2], rr[3] };
                vfloat4 s1 = { rr[4], rr[5], rr[6], rr[7] };
                __builtin_nontemporal_store(s0, reinterpret_cast<vfloat4*>(op));
                __builtin_nontemporal_store(s1, reinterpret_cast<vfloat4*>(op + 4));
            }
        }
    }
}

extern "C" void kernel_launch(void* const* d_in, const int* in_sizes, int n_in,
                              void* d_out, int out_size, void* d_ws, size_t ws_size,
                              hipStream_t stream)
{
    const float* x     = (const float*)d_in[0];
    const float* dct   = (const float*)d_in[1];
    const float* scale = (const float*)d_in[2];
    float* out = (float*)d_out;

    int nblocks = in_sizes[0] / 64;   // number of 8x8 tiles (262144*3)
    int block = 256;
    int grid  = 2048;                 // 8192 waves; 49152 tiles -> 6 iters exact

    dct2d_kernel<<<grid, block, 0, stream>>>(x, dct, scale, out, nblocks);
}